// Round 2
// baseline (485.248 us; speedup 1.0000x reference)
//
#include <hip/hip_runtime.h>
#include <hip/hip_bf16.h>
#include <stdint.h>

// ws layout (bytes):
//   0  : unsigned minkey   (monotone float key, atomicMin)
//   4  : unsigned maxkey   (monotone float key, atomicMax)
//   8  : u64 s_fx          (sum,  fixed point 2^20, two's-complement wrap)
//   16 : u64 ss_fx         (sum of squares, fixed point 2^20)
//   32 : unsigned hist[64]
//
// out layout (134 x float32): [mn, mx, num, s, ss, edges[65], counts[64]]
// (reference outputs are float32/int32 -> harness d_out is float*, NOT bf16;
//  round-1 forensics: bf16 writes put bf16(mn)=0xC0AD into the high half of
//  float element 2, read back as -5.40625.)

__device__ __forceinline__ unsigned fkey(float f) {
    unsigned u = __float_as_uint(f);
    return (u & 0x80000000u) ? ~u : (u | 0x80000000u);
}
__device__ __forceinline__ float funkey(unsigned k) {
    unsigned u = (k & 0x80000000u) ? (k ^ 0x80000000u) : ~k;
    return __uint_as_float(u);
}

__global__ void k_init(unsigned* minkey, unsigned* maxkey,
                       unsigned long long* sfx, unsigned long long* ssfx,
                       unsigned* ghist) {
    int t = threadIdx.x;
    if (t < 64) ghist[t] = 0u;
    if (t == 64) *minkey = 0xFFFFFFFFu;
    if (t == 65) *maxkey = 0u;
    if (t == 66) *sfx = 0ull;
    if (t == 67) *ssfx = 0ull;
}

__global__ __launch_bounds__(256) void k_reduce(
    const float* __restrict__ x, long long n,
    unsigned* __restrict__ ws_minkey, unsigned* __restrict__ ws_maxkey,
    unsigned long long* __restrict__ ws_sfx, unsigned long long* __restrict__ ws_ssfx)
{
    const float4* __restrict__ x4 = (const float4*)x;
    const long long n4 = n >> 2;
    float lmin = INFINITY, lmax = -INFINITY;
    float ls = 0.0f, lss = 0.0f;
    const long long stride = (long long)gridDim.x * 256;
    for (long long i = (long long)blockIdx.x * 256 + threadIdx.x; i < n4; i += stride) {
        float4 v = x4[i];
        lmin = fminf(lmin, fminf(fminf(v.x, v.y), fminf(v.z, v.w)));
        lmax = fmaxf(lmax, fmaxf(fmaxf(v.x, v.y), fmaxf(v.z, v.w)));
        ls += (v.x + v.y) + (v.z + v.w);
        lss = fmaf(v.x, v.x, lss);
        lss = fmaf(v.y, v.y, lss);
        lss = fmaf(v.z, v.z, lss);
        lss = fmaf(v.w, v.w, lss);
    }
    // scalar tail (n % 4) — block 0 only
    if (blockIdx.x == 0 && (long long)threadIdx.x < (n & 3)) {
        float v = x[(n4 << 2) + threadIdx.x];
        lmin = fminf(lmin, v); lmax = fmaxf(lmax, v);
        ls += v; lss = fmaf(v, v, lss);
    }
    // wave-64 shuffle reduce
    #pragma unroll
    for (int off = 32; off > 0; off >>= 1) {
        lmin = fminf(lmin, __shfl_down(lmin, off, 64));
        lmax = fmaxf(lmax, __shfl_down(lmax, off, 64));
        ls  += __shfl_down(ls,  off, 64);
        lss += __shfl_down(lss, off, 64);
    }
    __shared__ float smin[4], smax[4], ssum[4], ssq[4];
    const int wave = threadIdx.x >> 6;
    if ((threadIdx.x & 63) == 0) {
        smin[wave] = lmin; smax[wave] = lmax; ssum[wave] = ls; ssq[wave] = lss;
    }
    __syncthreads();
    if (threadIdx.x == 0) {
        float bmin = fminf(fminf(smin[0], smin[1]), fminf(smin[2], smin[3]));
        float bmax = fmaxf(fmaxf(smax[0], smax[1]), fmaxf(smax[2], smax[3]));
        float bs   = (ssum[0] + ssum[1]) + (ssum[2] + ssum[3]);
        float bss  = (ssq[0]  + ssq[1])  + (ssq[2]  + ssq[3]);
        atomicMin(ws_minkey, fkey(bmin));
        atomicMax(ws_maxkey, fkey(bmax));
        atomicAdd(ws_sfx,  (unsigned long long)(long long)((double)bs  * 1048576.0));
        atomicAdd(ws_ssfx, (unsigned long long)(long long)((double)bss * 1048576.0));
    }
}

__global__ __launch_bounds__(256) void k_hist(
    const float* __restrict__ x, long long n,
    const unsigned* __restrict__ ws_minkey, const unsigned* __restrict__ ws_maxkey,
    unsigned* __restrict__ ghist)
{
    // 32 LDS copies of a 64-bin histogram, layout hl[bin*32 + copy]:
    // copy = lane&31 -> every lane always addresses its own bank; worst case
    // 2-way alias (lane vs lane+32), which is free on gfx950 (m136).
    __shared__ unsigned hl[64 * 32];
    for (int i = threadIdx.x; i < 64 * 32; i += 256) hl[i] = 0u;

    const float mn  = funkey(*ws_minkey);
    const float mx  = funkey(*ws_maxkey);
    const float d   = __fsub_rn(mx, mn);
    const float inv = __fdiv_rn(64.0f, d);
    const float base = -mn * inv;   // bin ~= fma(v, inv, base)
    __syncthreads();

    const float4* __restrict__ x4 = (const float4*)x;
    const long long n4 = n >> 2;
    const unsigned c = threadIdx.x & 31u;
    const long long stride = (long long)gridDim.x * 256;
    for (long long i = (long long)blockIdx.x * 256 + threadIdx.x; i < n4; i += stride) {
        float4 v = x4[i];
        int j0 = (int)fmaf(v.x, inv, base); j0 = j0 > 63 ? 63 : j0;
        int j1 = (int)fmaf(v.y, inv, base); j1 = j1 > 63 ? 63 : j1;
        int j2 = (int)fmaf(v.z, inv, base); j2 = j2 > 63 ? 63 : j2;
        int j3 = (int)fmaf(v.w, inv, base); j3 = j3 > 63 ? 63 : j3;
        atomicAdd(&hl[(unsigned)j0 * 32u + c], 1u);
        atomicAdd(&hl[(unsigned)j1 * 32u + c], 1u);
        atomicAdd(&hl[(unsigned)j2 * 32u + c], 1u);
        atomicAdd(&hl[(unsigned)j3 * 32u + c], 1u);
    }
    // scalar tail — block 0 only
    if (blockIdx.x == 0 && (long long)threadIdx.x < (n & 3)) {
        float v = x[(n4 << 2) + threadIdx.x];
        int j = (int)fmaf(v, inv, base); j = j > 63 ? 63 : j;
        atomicAdd(&hl[(unsigned)j * 32u + c], 1u);
    }
    __syncthreads();
    if (threadIdx.x < 64) {
        const unsigned b = threadIdx.x;
        unsigned s = 0;
        #pragma unroll
        for (unsigned k = 0; k < 32; ++k)
            s += hl[b * 32u + ((k + b) & 31u)];   // rotated: conflict-free
        atomicAdd(&ghist[b], s);
    }
}

__global__ void k_fin(const unsigned* ws_minkey, const unsigned* ws_maxkey,
                      const unsigned long long* ws_sfx, const unsigned long long* ws_ssfx,
                      const unsigned* ghist, float* out, float fnum)
{
    const int t = threadIdx.x;
    const float mn = funkey(*ws_minkey);
    const float mx = funkey(*ws_maxkey);
    const float d  = __fsub_rn(mx, mn);
    if (t == 0) out[0] = mn;
    else if (t == 1) out[1] = mx;
    else if (t == 2) out[2] = fnum;
    else if (t == 3) out[3] = (float)((double)(long long)(*ws_sfx)  * 9.5367431640625e-07);
    else if (t == 4) out[4] = (float)((double)(long long)(*ws_ssfx) * 9.5367431640625e-07);
    else if (t >= 5 && t < 70) {
        int i = t - 5;
        // match jnp: edges[i] = f32(mn + f32(f32(mx-mn) * f32(i/64))), unfused
        out[t] = __fadd_rn(mn, __fmul_rn(d, (float)i * 0.015625f));
    } else if (t >= 70 && t < 134) {
        int b = t - 70;
        unsigned cv = ghist[b] + (b == 63 ? 1u : 0u);  // ref adds literal +1 to last bin
        out[t] = (float)cv;
    }
}

extern "C" void kernel_launch(void* const* d_in, const int* in_sizes, int n_in,
                              void* d_out, int out_size, void* d_ws, size_t ws_size,
                              hipStream_t stream)
{
    const float* x = (const float*)d_in[0];
    const long long n = (long long)in_sizes[0];

    unsigned* minkey = (unsigned*)d_ws;
    unsigned* maxkey = minkey + 1;
    unsigned long long* sfx  = (unsigned long long*)((char*)d_ws + 8);
    unsigned long long* ssfx = (unsigned long long*)((char*)d_ws + 16);
    unsigned* ghist = (unsigned*)((char*)d_ws + 32);

    k_init<<<1, 128, 0, stream>>>(minkey, maxkey, sfx, ssfx, ghist);

    const int blocks = 2048;  // 8 blocks/CU, grid-stride
    k_reduce<<<blocks, 256, 0, stream>>>(x, n, minkey, maxkey, sfx, ssfx);
    k_hist<<<blocks, 256, 0, stream>>>(x, n, minkey, maxkey, ghist);
    k_fin<<<1, 192, 0, stream>>>(minkey, maxkey, sfx, ssfx, ghist,
                                 (float*)d_out, (float)n);
}

// Round 3
// 466.228 us; speedup vs baseline: 1.0408x; 1.0408x over previous
//
#include <hip/hip_runtime.h>
#include <hip/hip_bf16.h>
#include <stdint.h>

// ws layout (bytes):
//   0  : unsigned minkey   (monotone float key, atomicMin)
//   4  : unsigned maxkey   (monotone float key, atomicMax)
//   8  : u64 s_fx          (sum,  fixed point 2^20)
//   16 : u64 ss_fx         (sum of squares, fixed point 2^20)
//   32 : unsigned hist[64]
//
// out layout (134 x float32): [mn, mx, num, s, ss, edges[65], counts[64]]
//
// R2 post-mortem: VGPR=12 -> one float4 in flight/thread -> latency-bound at
// 1.5 TB/s effective. Fix: 8 independent loads in flight per thread (ILP).

__device__ __forceinline__ unsigned fkey(float f) {
    unsigned u = __float_as_uint(f);
    return (u & 0x80000000u) ? ~u : (u | 0x80000000u);
}
__device__ __forceinline__ float funkey(unsigned k) {
    unsigned u = (k & 0x80000000u) ? (k ^ 0x80000000u) : ~k;
    return __uint_as_float(u);
}

__global__ void k_init(unsigned* minkey, unsigned* maxkey,
                       unsigned long long* sfx, unsigned long long* ssfx,
                       unsigned* ghist) {
    int t = threadIdx.x;
    if (t < 64) ghist[t] = 0u;
    if (t == 64) *minkey = 0xFFFFFFFFu;
    if (t == 65) *maxkey = 0u;
    if (t == 66) *sfx = 0ull;
    if (t == 67) *ssfx = 0ull;
}

__global__ __launch_bounds__(256) void k_reduce(
    const float* __restrict__ x, long long n,
    unsigned* __restrict__ ws_minkey, unsigned* __restrict__ ws_maxkey,
    unsigned long long* __restrict__ ws_sfx, unsigned long long* __restrict__ ws_ssfx)
{
    const float4* __restrict__ x4 = (const float4*)x;
    const long long n4 = n >> 2;
    const long long stride = (long long)gridDim.x * 256;
    float lmin = INFINITY, lmax = -INFINITY;
    float ls = 0.0f, lss = 0.0f;

    long long i = (long long)blockIdx.x * 256 + threadIdx.x;
    // main loop: 8 independent float4 loads in flight
    for (; i + 7 * stride < n4; i += 8 * stride) {
        float4 v[8];
        #pragma unroll
        for (int k = 0; k < 8; ++k) v[k] = x4[i + k * stride];
        #pragma unroll
        for (int k = 0; k < 8; ++k) {
            lmin = fminf(lmin, fminf(fminf(v[k].x, v[k].y), fminf(v[k].z, v[k].w)));
            lmax = fmaxf(lmax, fmaxf(fmaxf(v[k].x, v[k].y), fmaxf(v[k].z, v[k].w)));
            ls += (v[k].x + v[k].y) + (v[k].z + v[k].w);
            lss = fmaf(v[k].x, v[k].x, lss);
            lss = fmaf(v[k].y, v[k].y, lss);
            lss = fmaf(v[k].z, v[k].z, lss);
            lss = fmaf(v[k].w, v[k].w, lss);
        }
    }
    // remainder grid-stride
    for (; i < n4; i += stride) {
        float4 v = x4[i];
        lmin = fminf(lmin, fminf(fminf(v.x, v.y), fminf(v.z, v.w)));
        lmax = fmaxf(lmax, fmaxf(fmaxf(v.x, v.y), fmaxf(v.z, v.w)));
        ls += (v.x + v.y) + (v.z + v.w);
        lss = fmaf(v.x, v.x, lss);
        lss = fmaf(v.y, v.y, lss);
        lss = fmaf(v.z, v.z, lss);
        lss = fmaf(v.w, v.w, lss);
    }
    // scalar tail (n % 4) — block 0 only
    if (blockIdx.x == 0 && (long long)threadIdx.x < (n & 3)) {
        float v = x[(n4 << 2) + threadIdx.x];
        lmin = fminf(lmin, v); lmax = fmaxf(lmax, v);
        ls += v; lss = fmaf(v, v, lss);
    }
    // wave-64 shuffle reduce
    #pragma unroll
    for (int off = 32; off > 0; off >>= 1) {
        lmin = fminf(lmin, __shfl_down(lmin, off, 64));
        lmax = fmaxf(lmax, __shfl_down(lmax, off, 64));
        ls  += __shfl_down(ls,  off, 64);
        lss += __shfl_down(lss, off, 64);
    }
    __shared__ float smin[4], smax[4], ssum[4], ssq[4];
    const int wave = threadIdx.x >> 6;
    if ((threadIdx.x & 63) == 0) {
        smin[wave] = lmin; smax[wave] = lmax; ssum[wave] = ls; ssq[wave] = lss;
    }
    __syncthreads();
    if (threadIdx.x == 0) {
        float bmin = fminf(fminf(smin[0], smin[1]), fminf(smin[2], smin[3]));
        float bmax = fmaxf(fmaxf(smax[0], smax[1]), fmaxf(smax[2], smax[3]));
        float bs   = (ssum[0] + ssum[1]) + (ssum[2] + ssum[3]);
        float bss  = (ssq[0]  + ssq[1])  + (ssq[2]  + ssq[3]);
        atomicMin(ws_minkey, fkey(bmin));
        atomicMax(ws_maxkey, fkey(bmax));
        atomicAdd(ws_sfx,  (unsigned long long)(long long)((double)bs  * 1048576.0));
        atomicAdd(ws_ssfx, (unsigned long long)(long long)((double)bss * 1048576.0));
    }
}

__global__ __launch_bounds__(256) void k_hist(
    const float* __restrict__ x, long long n,
    const unsigned* __restrict__ ws_minkey, const unsigned* __restrict__ ws_maxkey,
    unsigned* __restrict__ ghist)
{
    // 32 LDS copies of a 64-bin histogram, layout hl[bin*32 + copy]:
    // copy = lane&31 -> every lane always addresses its own bank; worst case
    // 2-way alias (lane vs lane+32), which is free on gfx950 (m136).
    __shared__ unsigned hl[64 * 32];
    for (int i = threadIdx.x; i < 64 * 32; i += 256) hl[i] = 0u;

    const float mn  = funkey(*ws_minkey);
    const float mx  = funkey(*ws_maxkey);
    const float d   = __fsub_rn(mx, mn);
    const float inv = __fdiv_rn(64.0f, d);
    const float base = -mn * inv;   // bin ~= fma(v, inv, base)
    __syncthreads();

    const float4* __restrict__ x4 = (const float4*)x;
    const long long n4 = n >> 2;
    const unsigned c = threadIdx.x & 31u;
    const long long stride = (long long)gridDim.x * 256;

    long long i = (long long)blockIdx.x * 256 + threadIdx.x;
    // main loop: 8 independent float4 loads in flight
    for (; i + 7 * stride < n4; i += 8 * stride) {
        float4 v[8];
        #pragma unroll
        for (int k = 0; k < 8; ++k) v[k] = x4[i + k * stride];
        #pragma unroll
        for (int k = 0; k < 8; ++k) {
            int j0 = (int)fmaf(v[k].x, inv, base); j0 = j0 > 63 ? 63 : j0;
            int j1 = (int)fmaf(v[k].y, inv, base); j1 = j1 > 63 ? 63 : j1;
            int j2 = (int)fmaf(v[k].z, inv, base); j2 = j2 > 63 ? 63 : j2;
            int j3 = (int)fmaf(v[k].w, inv, base); j3 = j3 > 63 ? 63 : j3;
            atomicAdd(&hl[(unsigned)j0 * 32u + c], 1u);
            atomicAdd(&hl[(unsigned)j1 * 32u + c], 1u);
            atomicAdd(&hl[(unsigned)j2 * 32u + c], 1u);
            atomicAdd(&hl[(unsigned)j3 * 32u + c], 1u);
        }
    }
    // remainder grid-stride
    for (; i < n4; i += stride) {
        float4 v = x4[i];
        int j0 = (int)fmaf(v.x, inv, base); j0 = j0 > 63 ? 63 : j0;
        int j1 = (int)fmaf(v.y, inv, base); j1 = j1 > 63 ? 63 : j1;
        int j2 = (int)fmaf(v.z, inv, base); j2 = j2 > 63 ? 63 : j2;
        int j3 = (int)fmaf(v.w, inv, base); j3 = j3 > 63 ? 63 : j3;
        atomicAdd(&hl[(unsigned)j0 * 32u + c], 1u);
        atomicAdd(&hl[(unsigned)j1 * 32u + c], 1u);
        atomicAdd(&hl[(unsigned)j2 * 32u + c], 1u);
        atomicAdd(&hl[(unsigned)j3 * 32u + c], 1u);
    }
    // scalar tail — block 0 only
    if (blockIdx.x == 0 && (long long)threadIdx.x < (n & 3)) {
        float v = x[(n4 << 2) + threadIdx.x];
        int j = (int)fmaf(v, inv, base); j = j > 63 ? 63 : j;
        atomicAdd(&hl[(unsigned)j * 32u + c], 1u);
    }
    __syncthreads();
    if (threadIdx.x < 64) {
        const unsigned b = threadIdx.x;
        unsigned s = 0;
        #pragma unroll
        for (unsigned k = 0; k < 32; ++k)
            s += hl[b * 32u + ((k + b) & 31u)];   // rotated: conflict-free
        atomicAdd(&ghist[b], s);
    }
}

__global__ void k_fin(const unsigned* ws_minkey, const unsigned* ws_maxkey,
                      const unsigned long long* ws_sfx, const unsigned long long* ws_ssfx,
                      const unsigned* ghist, float* out, float fnum)
{
    const int t = threadIdx.x;
    const float mn = funkey(*ws_minkey);
    const float mx = funkey(*ws_maxkey);
    const float d  = __fsub_rn(mx, mn);
    if (t == 0) out[0] = mn;
    else if (t == 1) out[1] = mx;
    else if (t == 2) out[2] = fnum;
    else if (t == 3) out[3] = (float)((double)(long long)(*ws_sfx)  * 9.5367431640625e-07);
    else if (t == 4) out[4] = (float)((double)(long long)(*ws_ssfx) * 9.5367431640625e-07);
    else if (t >= 5 && t < 70) {
        int i = t - 5;
        // match jnp: edges[i] = f32(mn + f32(f32(mx-mn) * f32(i/64))), unfused
        out[t] = __fadd_rn(mn, __fmul_rn(d, (float)i * 0.015625f));
    } else if (t >= 70 && t < 134) {
        int b = t - 70;
        unsigned cv = ghist[b] + (b == 63 ? 1u : 0u);  // ref adds literal +1 to last bin
        out[t] = (float)cv;
    }
}

extern "C" void kernel_launch(void* const* d_in, const int* in_sizes, int n_in,
                              void* d_out, int out_size, void* d_ws, size_t ws_size,
                              hipStream_t stream)
{
    const float* x = (const float*)d_in[0];
    const long long n = (long long)in_sizes[0];

    unsigned* minkey = (unsigned*)d_ws;
    unsigned* maxkey = minkey + 1;
    unsigned long long* sfx  = (unsigned long long*)((char*)d_ws + 8);
    unsigned long long* ssfx = (unsigned long long*)((char*)d_ws + 16);
    unsigned* ghist = (unsigned*)((char*)d_ws + 32);

    k_init<<<1, 128, 0, stream>>>(minkey, maxkey, sfx, ssfx, ghist);

    const int blocks = 2048;  // 8 blocks/CU, grid-stride
    k_reduce<<<blocks, 256, 0, stream>>>(x, n, minkey, maxkey, sfx, ssfx);
    k_hist<<<blocks, 256, 0, stream>>>(x, n, minkey, maxkey, ghist);
    k_fin<<<1, 192, 0, stream>>>(minkey, maxkey, sfx, ssfx, ghist,
                                 (float*)d_out, (float)n);
}

// Round 4
// 434.633 us; speedup vs baseline: 1.1165x; 1.0727x over previous
//
#include <hip/hip_runtime.h>
#include <hip/hip_bf16.h>
#include <stdint.h>

// ws layout (bytes):
//   0  : unsigned minkey   (monotone float key, atomicMin)
//   4  : unsigned maxkey   (monotone float key, atomicMax)
//   8  : u64 s_fx          (sum,  fixed point 2^20)
//   16 : u64 ss_fx         (sum of squares, fixed point 2^20)
//   32 : unsigned hist[64]
//
// out layout (134 x float32): [mn, mx, num, s, ss, edges[65], counts[64]]
//
// R3 post-mortem: grid-stride unroll was serialized by the compiler (VGPR=36,
// 8 MB strides need a 64-bit addr pair per load). L3-warm replays ran the
// same 155 us -> latency-bound at ~2 loads in flight. Fix: thread-contiguous
// 128 B chunks -> one addr pair + 8 immediate-offset loads, truly independent.

__device__ __forceinline__ unsigned fkey(float f) {
    unsigned u = __float_as_uint(f);
    return (u & 0x80000000u) ? ~u : (u | 0x80000000u);
}
__device__ __forceinline__ float funkey(unsigned k) {
    unsigned u = (k & 0x80000000u) ? (k ^ 0x80000000u) : ~k;
    return __uint_as_float(u);
}

__global__ void k_init(unsigned* minkey, unsigned* maxkey,
                       unsigned long long* sfx, unsigned long long* ssfx,
                       unsigned* ghist) {
    int t = threadIdx.x;
    if (t < 64) ghist[t] = 0u;
    if (t == 64) *minkey = 0xFFFFFFFFu;
    if (t == 65) *maxkey = 0u;
    if (t == 66) *sfx = 0ull;
    if (t == 67) *ssfx = 0ull;
}

__global__ __launch_bounds__(256) void k_reduce(
    const float* __restrict__ x, long long n,
    unsigned* __restrict__ ws_minkey, unsigned* __restrict__ ws_maxkey,
    unsigned long long* __restrict__ ws_sfx, unsigned long long* __restrict__ ws_ssfx)
{
    const float4* __restrict__ x4 = (const float4*)x;
    const long long n4 = n >> 2;          // # float4
    const long long nchunk = n4 >> 3;     // # 8-float4 (128 B) chunks
    const long long gstride = (long long)gridDim.x * 256;

    float lmin = INFINITY, lmax = -INFINITY;
    float ls = 0.0f, lss = 0.0f;

    for (long long c = (long long)blockIdx.x * 256 + threadIdx.x; c < nchunk; c += gstride) {
        const float4* __restrict__ p = x4 + (c << 3);
        // 8 independent loads off ONE base pointer (imm offsets 0..112 B)
        float4 v0 = p[0], v1 = p[1], v2 = p[2], v3 = p[3];
        float4 v4 = p[4], v5 = p[5], v6 = p[6], v7 = p[7];
        float4 vv[8] = {v0, v1, v2, v3, v4, v5, v6, v7};
        #pragma unroll
        for (int k = 0; k < 8; ++k) {
            float4 v = vv[k];
            lmin = fminf(lmin, fminf(fminf(v.x, v.y), fminf(v.z, v.w)));
            lmax = fmaxf(lmax, fmaxf(fmaxf(v.x, v.y), fmaxf(v.z, v.w)));
            ls += (v.x + v.y) + (v.z + v.w);
            lss = fmaf(v.x, v.x, lss);
            lss = fmaf(v.y, v.y, lss);
            lss = fmaf(v.z, v.z, lss);
            lss = fmaf(v.w, v.w, lss);
        }
    }
    // leftover float4s (n4 % 8) — block 0
    {
        const long long done4 = nchunk << 3;
        if (blockIdx.x == 0 && (long long)threadIdx.x < (n4 - done4)) {
            float4 v = x4[done4 + threadIdx.x];
            lmin = fminf(lmin, fminf(fminf(v.x, v.y), fminf(v.z, v.w)));
            lmax = fmaxf(lmax, fmaxf(fmaxf(v.x, v.y), fmaxf(v.z, v.w)));
            ls += (v.x + v.y) + (v.z + v.w);
            lss = fmaf(v.x, v.x, lss); lss = fmaf(v.y, v.y, lss);
            lss = fmaf(v.z, v.z, lss); lss = fmaf(v.w, v.w, lss);
        }
    }
    // scalar tail (n % 4) — block 0
    if (blockIdx.x == 0 && (long long)threadIdx.x < (n & 3)) {
        float v = x[(n4 << 2) + threadIdx.x];
        lmin = fminf(lmin, v); lmax = fmaxf(lmax, v);
        ls += v; lss = fmaf(v, v, lss);
    }
    // wave-64 shuffle reduce
    #pragma unroll
    for (int off = 32; off > 0; off >>= 1) {
        lmin = fminf(lmin, __shfl_down(lmin, off, 64));
        lmax = fmaxf(lmax, __shfl_down(lmax, off, 64));
        ls  += __shfl_down(ls,  off, 64);
        lss += __shfl_down(lss, off, 64);
    }
    __shared__ float smin[4], smax[4], ssum[4], ssq[4];
    const int wave = threadIdx.x >> 6;
    if ((threadIdx.x & 63) == 0) {
        smin[wave] = lmin; smax[wave] = lmax; ssum[wave] = ls; ssq[wave] = lss;
    }
    __syncthreads();
    if (threadIdx.x == 0) {
        float bmin = fminf(fminf(smin[0], smin[1]), fminf(smin[2], smin[3]));
        float bmax = fmaxf(fmaxf(smax[0], smax[1]), fmaxf(smax[2], smax[3]));
        float bs   = (ssum[0] + ssum[1]) + (ssum[2] + ssum[3]);
        float bss  = (ssq[0]  + ssq[1])  + (ssq[2]  + ssq[3]);
        atomicMin(ws_minkey, fkey(bmin));
        atomicMax(ws_maxkey, fkey(bmax));
        atomicAdd(ws_sfx,  (unsigned long long)(long long)((double)bs  * 1048576.0));
        atomicAdd(ws_ssfx, (unsigned long long)(long long)((double)bss * 1048576.0));
    }
}

__global__ __launch_bounds__(256) void k_hist(
    const float* __restrict__ x, long long n,
    const unsigned* __restrict__ ws_minkey, const unsigned* __restrict__ ws_maxkey,
    unsigned* __restrict__ ghist)
{
    // 32 LDS copies of a 64-bin histogram, layout hl[bin*32 + copy]:
    // copy = lane&31 -> every lane always addresses its own bank; worst case
    // 2-way alias (lane vs lane+32), which is free on gfx950 (m136).
    __shared__ unsigned hl[64 * 32];
    for (int i = threadIdx.x; i < 64 * 32; i += 256) hl[i] = 0u;

    const float mn  = funkey(*ws_minkey);
    const float mx  = funkey(*ws_maxkey);
    const float d   = __fsub_rn(mx, mn);
    const float inv = __fdiv_rn(64.0f, d);
    const float base = -mn * inv;   // bin ~= fma(v, inv, base)
    __syncthreads();

    const float4* __restrict__ x4 = (const float4*)x;
    const long long n4 = n >> 2;
    const long long nchunk = n4 >> 3;
    const unsigned c = threadIdx.x & 31u;
    const long long gstride = (long long)gridDim.x * 256;

    auto binup = [&](float4 v) {
        int j0 = (int)fmaf(v.x, inv, base); j0 = j0 > 63 ? 63 : j0;
        int j1 = (int)fmaf(v.y, inv, base); j1 = j1 > 63 ? 63 : j1;
        int j2 = (int)fmaf(v.z, inv, base); j2 = j2 > 63 ? 63 : j2;
        int j3 = (int)fmaf(v.w, inv, base); j3 = j3 > 63 ? 63 : j3;
        atomicAdd(&hl[(unsigned)j0 * 32u + c], 1u);
        atomicAdd(&hl[(unsigned)j1 * 32u + c], 1u);
        atomicAdd(&hl[(unsigned)j2 * 32u + c], 1u);
        atomicAdd(&hl[(unsigned)j3 * 32u + c], 1u);
    };

    for (long long ci = (long long)blockIdx.x * 256 + threadIdx.x; ci < nchunk; ci += gstride) {
        const float4* __restrict__ p = x4 + (ci << 3);
        float4 v0 = p[0], v1 = p[1], v2 = p[2], v3 = p[3];
        float4 v4 = p[4], v5 = p[5], v6 = p[6], v7 = p[7];
        binup(v0); binup(v1); binup(v2); binup(v3);
        binup(v4); binup(v5); binup(v6); binup(v7);
    }
    // leftover float4s — block 0
    {
        const long long done4 = nchunk << 3;
        if (blockIdx.x == 0 && (long long)threadIdx.x < (n4 - done4))
            binup(x4[done4 + threadIdx.x]);
    }
    // scalar tail — block 0
    if (blockIdx.x == 0 && (long long)threadIdx.x < (n & 3)) {
        float v = x[(n4 << 2) + threadIdx.x];
        int j = (int)fmaf(v, inv, base); j = j > 63 ? 63 : j;
        atomicAdd(&hl[(unsigned)j * 32u + c], 1u);
    }
    __syncthreads();
    if (threadIdx.x < 64) {
        const unsigned b = threadIdx.x;
        unsigned s = 0;
        #pragma unroll
        for (unsigned k = 0; k < 32; ++k)
            s += hl[b * 32u + ((k + b) & 31u)];   // rotated: conflict-free
        atomicAdd(&ghist[b], s);
    }
}

__global__ void k_fin(const unsigned* ws_minkey, const unsigned* ws_maxkey,
                      const unsigned long long* ws_sfx, const unsigned long long* ws_ssfx,
                      const unsigned* ghist, float* out, float fnum)
{
    const int t = threadIdx.x;
    const float mn = funkey(*ws_minkey);
    const float mx = funkey(*ws_maxkey);
    const float d  = __fsub_rn(mx, mn);
    if (t == 0) out[0] = mn;
    else if (t == 1) out[1] = mx;
    else if (t == 2) out[2] = fnum;
    else if (t == 3) out[3] = (float)((double)(long long)(*ws_sfx)  * 9.5367431640625e-07);
    else if (t == 4) out[4] = (float)((double)(long long)(*ws_ssfx) * 9.5367431640625e-07);
    else if (t >= 5 && t < 70) {
        int i = t - 5;
        // match jnp: edges[i] = f32(mn + f32(f32(mx-mn) * f32(i/64))), unfused
        out[t] = __fadd_rn(mn, __fmul_rn(d, (float)i * 0.015625f));
    } else if (t >= 70 && t < 134) {
        int b = t - 70;
        unsigned cv = ghist[b] + (b == 63 ? 1u : 0u);  // ref adds literal +1 to last bin
        out[t] = (float)cv;
    }
}

extern "C" void kernel_launch(void* const* d_in, const int* in_sizes, int n_in,
                              void* d_out, int out_size, void* d_ws, size_t ws_size,
                              hipStream_t stream)
{
    const float* x = (const float*)d_in[0];
    const long long n = (long long)in_sizes[0];

    unsigned* minkey = (unsigned*)d_ws;
    unsigned* maxkey = minkey + 1;
    unsigned long long* sfx  = (unsigned long long*)((char*)d_ws + 8);
    unsigned long long* ssfx = (unsigned long long*)((char*)d_ws + 16);
    unsigned* ghist = (unsigned*)((char*)d_ws + 32);

    k_init<<<1, 128, 0, stream>>>(minkey, maxkey, sfx, ssfx, ghist);

    const int blocks = 2048;  // 8 blocks/CU
    k_reduce<<<blocks, 256, 0, stream>>>(x, n, minkey, maxkey, sfx, ssfx);
    k_hist<<<blocks, 256, 0, stream>>>(x, n, minkey, maxkey, ghist);
    k_fin<<<1, 192, 0, stream>>>(minkey, maxkey, sfx, ssfx, ghist,
                                 (float*)d_out, (float)n);
}

// Round 5
// 434.090 us; speedup vs baseline: 1.1179x; 1.0013x over previous
//
#include <hip/hip_runtime.h>
#include <hip/hip_bf16.h>
#include <stdint.h>

// ws layout (bytes):
//   0  : unsigned minkey   (monotone float key, atomicMin)
//   4  : unsigned maxkey   (monotone float key, atomicMax)
//   8  : u64 s_fx          (sum,  fixed point 2^20)
//   16 : u64 ss_fx         (sum of squares, fixed point 2^20)
//   32 : unsigned hist[64]
//
// out layout (134 x float32): [mn, mx, num, s, ss, edges[65], counts[64]]
//
// R4 post-mortem: per-thread-contiguous 128B chunks destroyed wave-level
// coalescing (64 distinct cache lines per load instr instead of 16) -> TA/L1
// transaction-bound. R5: wave-contiguous tiles. Each wave owns 8 KB/iter:
// lane addr = base + lane*16, 8 independent loads at +k*1024 (imm offsets
// 0..3072 off two base pointers). Coalesced AND 8-deep MLP.

__device__ __forceinline__ unsigned fkey(float f) {
    unsigned u = __float_as_uint(f);
    return (u & 0x80000000u) ? ~u : (u | 0x80000000u);
}
__device__ __forceinline__ float funkey(unsigned k) {
    unsigned u = (k & 0x80000000u) ? (k ^ 0x80000000u) : ~k;
    return __uint_as_float(u);
}

__global__ void k_init(unsigned* minkey, unsigned* maxkey,
                       unsigned long long* sfx, unsigned long long* ssfx,
                       unsigned* ghist) {
    int t = threadIdx.x;
    if (t < 64) ghist[t] = 0u;
    if (t == 64) *minkey = 0xFFFFFFFFu;
    if (t == 65) *maxkey = 0u;
    if (t == 66) *sfx = 0ull;
    if (t == 67) *ssfx = 0ull;
}

__global__ __launch_bounds__(256) void k_reduce(
    const float* __restrict__ x, long long n,
    unsigned* __restrict__ ws_minkey, unsigned* __restrict__ ws_maxkey,
    unsigned long long* __restrict__ ws_sfx, unsigned long long* __restrict__ ws_ssfx)
{
    const float4* __restrict__ x4 = (const float4*)x;
    const long long n4 = n >> 2;                       // # float4
    const int lane = threadIdx.x & 63;
    const int wv   = threadIdx.x >> 6;
    const long long gw     = (long long)blockIdx.x * 4 + wv;   // global wave id
    const long long nwaves = (long long)gridDim.x * 4;
    const long long per_iter = nwaves * 512;           // float4s per grid-iter

    float lmin = INFINITY, lmax = -INFINITY;
    float ls0 = 0.0f, ls1 = 0.0f, lq0 = 0.0f, lq1 = 0.0f;

    // main loop: wave-contiguous 8 KB tiles, 8 coalesced loads in flight
    for (long long base = gw * 512; base + 512 <= n4; base += per_iter) {
        const float4* __restrict__ p = x4 + base + lane;       // k=0..3: imm 0..3072
        const float4* __restrict__ q = p + 256;                // k=4..7: imm 0..3072
        float4 a0 = p[0], a1 = p[64], a2 = p[128], a3 = p[192];
        float4 a4 = q[0], a5 = q[64], a6 = q[128], a7 = q[192];
        float4 vv[8] = {a0, a1, a2, a3, a4, a5, a6, a7};
        #pragma unroll
        for (int k = 0; k < 8; ++k) {
            float4 v = vv[k];
            lmin = fminf(lmin, fminf(fminf(v.x, v.y), fminf(v.z, v.w)));
            lmax = fmaxf(lmax, fmaxf(fmaxf(v.x, v.y), fmaxf(v.z, v.w)));
            if (k & 1) {
                ls1 += (v.x + v.y) + (v.z + v.w);
                lq1 = fmaf(v.x, v.x, lq1); lq1 = fmaf(v.y, v.y, lq1);
                lq1 = fmaf(v.z, v.z, lq1); lq1 = fmaf(v.w, v.w, lq1);
            } else {
                ls0 += (v.x + v.y) + (v.z + v.w);
                lq0 = fmaf(v.x, v.x, lq0); lq0 = fmaf(v.y, v.y, lq0);
                lq0 = fmaf(v.z, v.z, lq0); lq0 = fmaf(v.w, v.w, lq0);
            }
        }
    }
    // remainder float4s (n4 % 512) — block 0 grid-stride
    {
        const long long rem_start = n4 & ~511LL;
        if (blockIdx.x == 0) {
            for (long long i = rem_start + threadIdx.x; i < n4; i += 256) {
                float4 v = x4[i];
                lmin = fminf(lmin, fminf(fminf(v.x, v.y), fminf(v.z, v.w)));
                lmax = fmaxf(lmax, fmaxf(fmaxf(v.x, v.y), fmaxf(v.z, v.w)));
                ls0 += (v.x + v.y) + (v.z + v.w);
                lq0 = fmaf(v.x, v.x, lq0); lq0 = fmaf(v.y, v.y, lq0);
                lq0 = fmaf(v.z, v.z, lq0); lq0 = fmaf(v.w, v.w, lq0);
            }
        }
    }
    // scalar tail (n % 4) — block 0
    if (blockIdx.x == 0 && (long long)threadIdx.x < (n & 3)) {
        float v = x[(n4 << 2) + threadIdx.x];
        lmin = fminf(lmin, v); lmax = fmaxf(lmax, v);
        ls0 += v; lq0 = fmaf(v, v, lq0);
    }
    float ls = ls0 + ls1, lss = lq0 + lq1;
    // wave-64 shuffle reduce
    #pragma unroll
    for (int off = 32; off > 0; off >>= 1) {
        lmin = fminf(lmin, __shfl_down(lmin, off, 64));
        lmax = fmaxf(lmax, __shfl_down(lmax, off, 64));
        ls  += __shfl_down(ls,  off, 64);
        lss += __shfl_down(lss, off, 64);
    }
    __shared__ float smin[4], smax[4], ssum[4], ssq[4];
    if ((threadIdx.x & 63) == 0) {
        smin[wv] = lmin; smax[wv] = lmax; ssum[wv] = ls; ssq[wv] = lss;
    }
    __syncthreads();
    if (threadIdx.x == 0) {
        float bmin = fminf(fminf(smin[0], smin[1]), fminf(smin[2], smin[3]));
        float bmax = fmaxf(fmaxf(smax[0], smax[1]), fmaxf(smax[2], smax[3]));
        float bs   = (ssum[0] + ssum[1]) + (ssum[2] + ssum[3]);
        float bss  = (ssq[0]  + ssq[1])  + (ssq[2]  + ssq[3]);
        atomicMin(ws_minkey, fkey(bmin));
        atomicMax(ws_maxkey, fkey(bmax));
        atomicAdd(ws_sfx,  (unsigned long long)(long long)((double)bs  * 1048576.0));
        atomicAdd(ws_ssfx, (unsigned long long)(long long)((double)bss * 1048576.0));
    }
}

__global__ __launch_bounds__(256) void k_hist(
    const float* __restrict__ x, long long n,
    const unsigned* __restrict__ ws_minkey, const unsigned* __restrict__ ws_maxkey,
    unsigned* __restrict__ ghist)
{
    // 32 LDS copies of a 64-bin histogram, hl[bin*32 + (lane&31)]:
    // every lane always hits its own bank; worst case 2-way (lane vs lane+32),
    // free on gfx950 (m136). 8 KB LDS.
    __shared__ unsigned hl[64 * 32];
    for (int i = threadIdx.x; i < 64 * 32; i += 256) hl[i] = 0u;

    const float mn  = funkey(*ws_minkey);
    const float mx  = funkey(*ws_maxkey);
    const float d   = __fsub_rn(mx, mn);
    const float inv = __fdiv_rn(64.0f, d);
    const float base = -mn * inv;   // bin ~= fma(v, inv, base)
    __syncthreads();

    const float4* __restrict__ x4 = (const float4*)x;
    const long long n4 = n >> 2;
    const unsigned c = threadIdx.x & 31u;
    const int lane = threadIdx.x & 63;
    const int wv   = threadIdx.x >> 6;
    const long long gw     = (long long)blockIdx.x * 4 + wv;
    const long long nwaves = (long long)gridDim.x * 4;
    const long long per_iter = nwaves * 512;

    auto binup = [&](float4 v) {
        int j0 = (int)fmaf(v.x, inv, base); j0 = j0 > 63 ? 63 : j0;
        int j1 = (int)fmaf(v.y, inv, base); j1 = j1 > 63 ? 63 : j1;
        int j2 = (int)fmaf(v.z, inv, base); j2 = j2 > 63 ? 63 : j2;
        int j3 = (int)fmaf(v.w, inv, base); j3 = j3 > 63 ? 63 : j3;
        atomicAdd(&hl[(unsigned)j0 * 32u + c], 1u);
        atomicAdd(&hl[(unsigned)j1 * 32u + c], 1u);
        atomicAdd(&hl[(unsigned)j2 * 32u + c], 1u);
        atomicAdd(&hl[(unsigned)j3 * 32u + c], 1u);
    };

    for (long long b = gw * 512; b + 512 <= n4; b += per_iter) {
        const float4* __restrict__ p = x4 + b + lane;
        const float4* __restrict__ q = p + 256;
        float4 a0 = p[0], a1 = p[64], a2 = p[128], a3 = p[192];
        float4 a4 = q[0], a5 = q[64], a6 = q[128], a7 = q[192];
        binup(a0); binup(a1); binup(a2); binup(a3);
        binup(a4); binup(a5); binup(a6); binup(a7);
    }
    // remainder float4s — block 0
    {
        const long long rem_start = n4 & ~511LL;
        if (blockIdx.x == 0)
            for (long long i = rem_start + threadIdx.x; i < n4; i += 256)
                binup(x4[i]);
    }
    // scalar tail — block 0
    if (blockIdx.x == 0 && (long long)threadIdx.x < (n & 3)) {
        float v = x[(n4 << 2) + threadIdx.x];
        int j = (int)fmaf(v, inv, base); j = j > 63 ? 63 : j;
        atomicAdd(&hl[(unsigned)j * 32u + c], 1u);
    }
    __syncthreads();
    if (threadIdx.x < 64) {
        const unsigned b = threadIdx.x;
        unsigned s = 0;
        #pragma unroll
        for (unsigned k = 0; k < 32; ++k)
            s += hl[b * 32u + ((k + b) & 31u)];   // rotated: conflict-free
        atomicAdd(&ghist[b], s);
    }
}

__global__ void k_fin(const unsigned* ws_minkey, const unsigned* ws_maxkey,
                      const unsigned long long* ws_sfx, const unsigned long long* ws_ssfx,
                      const unsigned* ghist, float* out, float fnum)
{
    const int t = threadIdx.x;
    const float mn = funkey(*ws_minkey);
    const float mx = funkey(*ws_maxkey);
    const float d  = __fsub_rn(mx, mn);
    if (t == 0) out[0] = mn;
    else if (t == 1) out[1] = mx;
    else if (t == 2) out[2] = fnum;
    else if (t == 3) out[3] = (float)((double)(long long)(*ws_sfx)  * 9.5367431640625e-07);
    else if (t == 4) out[4] = (float)((double)(long long)(*ws_ssfx) * 9.5367431640625e-07);
    else if (t >= 5 && t < 70) {
        int i = t - 5;
        // match jnp: edges[i] = f32(mn + f32(f32(mx-mn) * f32(i/64))), unfused
        out[t] = __fadd_rn(mn, __fmul_rn(d, (float)i * 0.015625f));
    } else if (t >= 70 && t < 134) {
        int b = t - 70;
        unsigned cv = ghist[b] + (b == 63 ? 1u : 0u);  // ref adds literal +1 to last bin
        out[t] = (float)cv;
    }
}

extern "C" void kernel_launch(void* const* d_in, const int* in_sizes, int n_in,
                              void* d_out, int out_size, void* d_ws, size_t ws_size,
                              hipStream_t stream)
{
    const float* x = (const float*)d_in[0];
    const long long n = (long long)in_sizes[0];

    unsigned* minkey = (unsigned*)d_ws;
    unsigned* maxkey = minkey + 1;
    unsigned long long* sfx  = (unsigned long long*)((char*)d_ws + 8);
    unsigned long long* ssfx = (unsigned long long*)((char*)d_ws + 16);
    unsigned* ghist = (unsigned*)((char*)d_ws + 32);

    k_init<<<1, 128, 0, stream>>>(minkey, maxkey, sfx, ssfx, ghist);

    const int blocks = 2048;  // 8 blocks/CU
    k_reduce<<<blocks, 256, 0, stream>>>(x, n, minkey, maxkey, sfx, ssfx);
    k_hist<<<blocks, 256, 0, stream>>>(x, n, minkey, maxkey, ghist);
    k_fin<<<1, 192, 0, stream>>>(minkey, maxkey, sfx, ssfx, ghist,
                                 (float*)d_out, (float)n);
}